// Round 1
// baseline (636.294 us; speedup 1.0000x reference)
//
#include <hip/hip_runtime.h>

using u16 = unsigned short;
using u32 = unsigned int;

typedef __bf16 bf16x8 __attribute__((ext_vector_type(8)));
typedef float  f32x4  __attribute__((ext_vector_type(4)));
typedef u16    u16x4  __attribute__((ext_vector_type(4)));
typedef u16    u16x8  __attribute__((ext_vector_type(8)));

#define MFMA16(a,b,c) __builtin_amdgcn_mfma_f32_16x16x32_bf16((a),(b),(c),0,0,0)

__device__ __forceinline__ u16 f2bf(float f){
    u32 u = __builtin_bit_cast(u32,f);
    u += 0x7FFFu + ((u>>16)&1u);
    return (u16)(u>>16);
}

__device__ __forceinline__ u16x4 pack4(f32x4 a){
    u16x4 p; p[0]=f2bf(a[0]); p[1]=f2bf(a[1]); p[2]=f2bf(a[2]); p[3]=f2bf(a[3]);
    return p;
}

#define QKSCALE 0.17677669529663687f

// geometry: B=8, N=16384(128x128), C=256, HEADS=8, d=32, WS=8 -> G=256, S=64
#define SA    264   // token-major staging row stride (elems; 528 B)
#define SC_QS 548   // scores q-stride (f32 words); 548%32==4 -> conflict-free D-store
#define SC_HS 68    // scores h-stride (f32 words)
#define P_QS  520   // P q-stride (elems); 520/2 % 32 == 4 -> 2-way (free) on PV reads
#define OP_S  260   // out-proj staging stride (f32 words)
#define SCR_W 40    // per-wave transpose scratch row stride (elems; 80 B, 16B-aligned)

// LDS map (bytes):
// region1 [0, 35072): staging xw|qw [64][264]u16 (33792) / scores f32[16][548] (35072) / att16[16][264] (8448)
// region2 [35072, 51712): P[16][520]u16 (16640) / oproj f32[16][260] (16640) / 8x wave scratch [16][40]u16 (10240)
#define R2_OFF    35072
#define OFF_WPRE  51712   // f32[64]
#define OFF_WPOST 51968   // f32[64]
#define OFF_BP    52224   // f32[256]
#define OFF_INV   53248   // f32[16*8]
#define LDS_BYTES 53760   // 3 blocks/CU (3*53760 = 161280 <= 163840)

// weight layout in d_ws (u16 elems): wqk[131072] (q-half pre-scaled) | wv[65536] | wproj[65536]
#define WS_WQK 0
#define WS_WV  131072
#define WS_WPJ 196608
#define WS_ELEMS 262144

__global__ __launch_bounds__(256) void convert_weights(
    const float* __restrict__ wqk, const float* __restrict__ wv,
    const float* __restrict__ wproj, u16* __restrict__ ws)
{
    for (int i = blockIdx.x*256 + threadIdx.x; i < WS_ELEMS; i += gridDim.x*256){
        float v;
        if (i < 131072){
            v = wqk[i];
            if (i < 65536) v *= QKSCALE;          // q-half rows 0..255: fold 1/sqrt(d)
        } else if (i < 196608) v = wv[i - 131072];
        else                   v = wproj[i - 196608];
        ws[i] = f2bf(v);
    }
}

template<bool WF32>
__device__ __forceinline__ bf16x8 ldb(const void* w, size_t off){
    if constexpr (!WF32) return *(const bf16x8*)((const u16*)w + off);
    const float* p = (const float*)w + off;
    f32x4 a = *(const f32x4*)p;
    f32x4 b = *(const f32x4*)(p + 4);
    u16x8 r;
    r[0]=f2bf(a[0]); r[1]=f2bf(a[1]); r[2]=f2bf(a[2]); r[3]=f2bf(a[3]);
    r[4]=f2bf(b[0]); r[5]=f2bf(b[1]); r[6]=f2bf(b[2]); r[7]=f2bf(b[3]);
    return __builtin_bit_cast(bf16x8, r);
}

template<bool WF32>
__global__ __launch_bounds__(512, 4) void gta_kernel(
    const float* __restrict__ x, const float* __restrict__ query,
    const void* __restrict__ wqk, const void* __restrict__ wv,
    const void* __restrict__ wproj, const float* __restrict__ bproj,
    const float* __restrict__ wpre, const float* __restrict__ wpost,
    float* __restrict__ outp)
{
    extern __shared__ char smem[];
    u16*   sStage = (u16*)(smem);                  // region1
    float* sSc    = (float*)(smem);                // region1 (scores)
    u16*   sAtt   = (u16*)(smem);                  // region1 (att, over dead scores)
    u16*   sP     = (u16*)(smem + R2_OFF);         // region2
    float* sOp    = (float*)(smem + R2_OFF);       // region2 (out-proj staging)
    float* sWpre  = (float*)(smem + OFF_WPRE);
    float* sWpost = (float*)(smem + OFF_WPOST);
    float* sBp    = (float*)(smem + OFF_BP);
    float* sInv   = (float*)(smem + OFF_INV);

    const int tid  = threadIdx.x;
    const int wid  = tid >> 6;      // wave = head
    const int lane = tid & 63;
    const int quad = lane >> 4;
    const int l16  = lane & 15;
    const int h    = wid;

    const int bid = blockIdx.x;     // 0..2047
    const int b  = bid >> 8;
    const int g  = bid & 255;
    const int gr = g >> 4, gc = g & 15;

    const int stok = tid >> 3, sseg = tid & 7;   // staging: 32 elems/thread
    const int srow = gr*8 + (stok>>3), scol = gc*8 + (stok&7);
    const size_t sgbase = (((size_t)b*16384) + (size_t)(srow*128 + scol))*256 + sseg*32;

    // per-wave transpose scratch (wave-local, lives in region2; dead before P/oproj use)
    u16* scr = (u16*)(smem + R2_OFF) + wid*(16*SCR_W);

    // ---- stage xw -> region1; small weights ----
    {
        const float* gx = x + sgbase;
        #pragma unroll
        for (int i=0;i<4;i++){
            f32x4 a = *(const f32x4*)(gx + i*8);
            f32x4 c = *(const f32x4*)(gx + i*8 + 4);
            u16x8 v;
            v[0]=f2bf(a[0]); v[1]=f2bf(a[1]); v[2]=f2bf(a[2]); v[3]=f2bf(a[3]);
            v[4]=f2bf(c[0]); v[5]=f2bf(c[1]); v[6]=f2bf(c[2]); v[7]=f2bf(c[3]);
            *(u16x8*)(sStage + stok*SA + sseg*32 + i*8) = v;
        }
    }
    if (tid < 64)       sWpre[tid]     = wpre[tid];
    else if (tid < 128) sWpost[tid-64] = wpost[tid-64];
    if (tid < 256)      sBp[tid]       = bproj[tid];
    __syncthreads();

    const float bias0 = sBp[wid*16 + l16];
    const float bias1 = sBp[(wid+8)*16 + l16];

    // ---- prefetch qw into regs (latency hidden under GEMM-V) ----
    f32x4 qreg[8];
    {
        const float* gq = query + sgbase;
        #pragma unroll
        for (int i=0;i<4;i++){
            qreg[2*i]   = *(const f32x4*)(gq + i*8);
            qreg[2*i+1] = *(const f32x4*)(gq + i*8 + 4);
        }
    }

    // ---- GEMM-V: v = xw @ Wv^T, wave h computes its own head's cols [h*32, h*32+32) ----
    // acc: D[tok-row][c-col], lane col = c; wave-local scratch transpose -> Vh B-fragments
    bf16x8 Vh[2][2];
    {
        f32x4 va[2][4];
        #pragma unroll
        for (int c=0;c<2;c++)
            #pragma unroll
            for (int rt=0;rt<4;rt++) va[c][rt] = (f32x4){0.f,0.f,0.f,0.f};
        #pragma unroll
        for (int ks=0; ks<8; ks++){
            bf16x8 w0 = ldb<WF32>(wv, (size_t)(h*32      + l16)*256 + ks*32 + quad*8);
            bf16x8 w1 = ldb<WF32>(wv, (size_t)(h*32 + 16 + l16)*256 + ks*32 + quad*8);
            const int ko = ks*32 + quad*8;
            #pragma unroll
            for (int rt=0; rt<4; rt++){
                bf16x8 a = *(const bf16x8*)(sStage + (rt*16+l16)*SA + ko);
                va[0][rt] = MFMA16(a, w0, va[0][rt]);
                va[1][rt] = MFMA16(a, w1, va[1][rt]);
            }
        }
        // scratch layout [c=l16][local tok 0..31 (+pad)]: write 4-token packs, read 8-token b128
        #pragma unroll
        for (int ctl=0; ctl<2; ctl++){
            #pragma unroll
            for (int ksh=0; ksh<2; ksh++){
                *(u16x4*)(scr + l16*SCR_W +      quad*4) = pack4(va[ctl][ksh*2  ]);
                *(u16x4*)(scr + l16*SCR_W + 16 + quad*4) = pack4(va[ctl][ksh*2+1]);
                Vh[ksh][ctl] = *(const bf16x8*)(scr + l16*SCR_W + quad*8);
            }
        }
    }
    __syncthreads();   // all waves done reading xw

    // ---- write prefetched qw -> region1 ----
    {
        #pragma unroll
        for (int i=0;i<4;i++){
            f32x4 a = qreg[2*i], c = qreg[2*i+1];
            u16x8 v;
            v[0]=f2bf(a[0]); v[1]=f2bf(a[1]); v[2]=f2bf(a[2]); v[3]=f2bf(a[3]);
            v[4]=f2bf(c[0]); v[5]=f2bf(c[1]); v[6]=f2bf(c[2]); v[7]=f2bf(c[3]);
            *(u16x8*)(sStage + stok*SA + sseg*32 + i*8) = v;
        }
    }
    __syncthreads();

    // ---- GEMM-QK fused, transposed orientation: q^T = Wq @ qw^T, k^T = Wk @ qw^T ----
    // A = weight fragment (rows = out channel), B = staged tokens (same loads as before,
    // just swapped MFMA operand order). D[d-row][tok-col]: lane col = tok.
    bf16x8 Qh[4], Kh[4];
    {
        f32x4 qa[2][4], ka[2][4];
        #pragma unroll
        for (int c=0;c<2;c++)
            #pragma unroll
            for (int t=0;t<4;t++){ qa[c][t] = (f32x4){0.f,0.f,0.f,0.f}; ka[c][t] = qa[c][t]; }
        #pragma unroll
        for (int ks=0; ks<8; ks++){
            const size_t ro = (size_t)(h*32 + l16)*256 + ks*32 + quad*8;
            bf16x8 wq0 = ldb<WF32>(wqk, ro);
            bf16x8 wq1 = ldb<WF32>(wqk, ro + 16*256);
            bf16x8 wk0 = ldb<WF32>(wqk, ro + 65536);
            bf16x8 wk1 = ldb<WF32>(wqk, ro + 65536 + 16*256);
            const int ko = ks*32 + quad*8;
            #pragma unroll
            for (int t=0; t<4; t++){
                bf16x8 bx = *(const bf16x8*)(sStage + (t*16+l16)*SA + ko);
                qa[0][t] = MFMA16(wq0, bx, qa[0][t]);
                qa[1][t] = MFMA16(wq1, bx, qa[1][t]);
                ka[0][t] = MFMA16(wk0, bx, ka[0][t]);
                ka[1][t] = MFMA16(wk1, bx, ka[1][t]);
            }
        }
        // scratch layout [tok=l16][d 0..31 (+pad)]: per q-tile write both 16-d halves, read b128
        #pragma unroll
        for (int t=0; t<4; t++){
            *(u16x4*)(scr + l16*SCR_W +      quad*4) = pack4(qa[0][t]);
            *(u16x4*)(scr + l16*SCR_W + 16 + quad*4) = pack4(qa[1][t]);
            Qh[t] = *(const bf16x8*)(scr + l16*SCR_W + quad*8);
        }
        #pragma unroll
        for (int t=0; t<4; t++){
            *(u16x4*)(scr + l16*SCR_W +      quad*4) = pack4(ka[0][t]);
            *(u16x4*)(scr + l16*SCR_W + 16 + quad*4) = pack4(ka[1][t]);
            Kh[t] = *(const bf16x8*)(scr + l16*SCR_W + quad*8);
        }
    }
    __syncthreads();   // qw dead; region1 becomes scores

    // ---- attention passes: 4 x 16 query rows; out-proj + coalesced store fused per pass ----
    #pragma unroll 1
    for (int p=0; p<4; p++){
        // scores: all operands in regs
        #pragma unroll
        for (int kt=0; kt<4; kt++){
            f32x4 z = {0.f,0.f,0.f,0.f};
            f32x4 d = MFMA16(Qh[p], Kh[kt], z);
            #pragma unroll
            for (int r=0;r<4;r++)
                sSc[(quad*4 + r)*SC_QS + h*SC_HS + kt*16 + l16] = d[r];
        }
        __syncthreads();
        // mix pre: scale (WF32 only; else folded in weights) + W_pre over heads
        #pragma unroll
        for (int i=0;i<2;i++){
            const int pp = tid + i*512;
            const int q = pp >> 6, k = pp & 63;
            float* rowp = sSc + q*SC_QS + k;
            float s0[8];
            #pragma unroll
            for (int hh=0;hh<8;hh++){
                float v = rowp[hh*SC_HS];
                if constexpr (WF32) v *= QKSCALE;
                s0[hh] = v;
            }
            #pragma unroll
            for (int hp=0;hp<8;hp++){
                float m = 0.f;
                #pragma unroll
                for (int hh=0;hh<8;hh++) m += sWpre[hp*8+hh]*s0[hh];
                rowp[hp*SC_HS] = m;
            }
        }
        __syncthreads();
        // softmax over keys: 256 threads, 2 per (q,h), pairwise shfl combine
        if (tid < 256){
            const int q = tid>>4, hh = (tid>>1)&7, half = tid&1;
            f32x4* r4 = (f32x4*)(sSc + q*SC_QS + hh*SC_HS + half*32);
            float mx = -1e30f;
            #pragma unroll
            for (int i=0;i<8;i++){ f32x4 v=r4[i];
                mx = fmaxf(mx, fmaxf(fmaxf(v[0],v[1]), fmaxf(v[2],v[3]))); }
            mx = fmaxf(mx, __shfl_xor(mx, 1));
            float sum = 0.f;
            #pragma unroll
            for (int i=0;i<8;i++){ f32x4 v=r4[i]; f32x4 e;
                e[0]=__expf(v[0]-mx); e[1]=__expf(v[1]-mx);
                e[2]=__expf(v[2]-mx); e[3]=__expf(v[3]-mx);
                sum += e[0]+e[1]+e[2]+e[3]; r4[i]=e; }
            sum += __shfl_xor(sum, 1);
            if (!half) sInv[q*8 + hh] = 1.f/sum;
        }
        __syncthreads();
        // mix post: (exp * inv) @ W_post^T -> P (bf16, A-operand layout [q][hp][k])
        #pragma unroll
        for (int i=0;i<2;i++){
            const int pp = tid + i*512;
            const int q = pp >> 6, k = pp & 63;
            const float* rowp = sSc + q*SC_QS + k;
            float s0[8];
            #pragma unroll
            for (int hh=0;hh<8;hh++) s0[hh] = rowp[hh*SC_HS] * sInv[q*8+hh];
            #pragma unroll
            for (int hp=0;hp<8;hp++){
                float m = 0.f;
                #pragma unroll
                for (int hh=0;hh<8;hh++) m += sWpost[hp*8+hh]*s0[hh];
                sP[q*P_QS + hp*64 + k] = f2bf(m);
            }
        }
        __syncthreads();
        // PV: wave=head; A=P_h [16q x 64k], B=Vh -> att16 [16][264] (over dead scores)
        #pragma unroll
        for (int ct=0; ct<2; ct++){
            f32x4 acc = {0.f,0.f,0.f,0.f};
            #pragma unroll
            for (int ks=0; ks<2; ks++){
                bf16x8 ap = *(const bf16x8*)(sP + l16*P_QS + h*64 + ks*32 + quad*8);
                acc = MFMA16(ap, Vh[ks][ct], acc);
            }
            #pragma unroll
            for (int r=0;r<4;r++)
                sAtt[(quad*4 + r)*SA + h*32 + ct*16 + l16] = f2bf(acc[r]);
        }
        __syncthreads();
        // out-proj for these 16 rows -> f32 staging (region2, over dead P)
        {
            f32x4 o0 = {0.f,0.f,0.f,0.f}, o1 = o0;
            #pragma unroll
            for (int ks=0; ks<8; ks++){
                bf16x8 a  = *(const bf16x8*)(sAtt + l16*SA + ks*32 + quad*8);
                bf16x8 w0 = ldb<WF32>(wproj, (size_t)((wid  )*16 + l16)*256 + ks*32 + quad*8);
                bf16x8 w1 = ldb<WF32>(wproj, (size_t)((wid+8)*16 + l16)*256 + ks*32 + quad*8);
                o0 = MFMA16(a, w0, o0);
                o1 = MFMA16(a, w1, o1);
            }
            #pragma unroll
            for (int r=0;r<4;r++){
                sOp[(quad*4+r)*OP_S + wid*16 + l16]     = o0[r] + bias0;
                sOp[(quad*4+r)*OP_S + (wid+8)*16 + l16] = o1[r] + bias1;
            }
        }
        __syncthreads();
        // coalesced store: each wave writes 2 full 1KB token rows (full 128B lines)
        {
            const int wtok = p*16 + (tid>>5);
            const int useg = tid & 31;
            const int rrow = gr*8 + (wtok>>3), ccol = gc*8 + (wtok&7);
            float* dst = outp + (((size_t)b*16384) + (size_t)(rrow*128 + ccol))*256 + useg*8;
            f32x4 v0 = *(const f32x4*)(sOp + (tid>>5)*OP_S + useg*8);
            f32x4 v1 = *(const f32x4*)(sOp + (tid>>5)*OP_S + useg*8 + 4);
            *(f32x4*)(dst)     = v0;
            *(f32x4*)(dst + 4) = v1;
        }
        // no trailing barrier: next pass's scores touch region1 only; 3 barriers separate
        // any wave's next region2 (P) write from stragglers' sOp reads
    }
}

extern "C" void kernel_launch(void* const* d_in, const int* in_sizes, int n_in,
                              void* d_out, int out_size, void* d_ws, size_t ws_size,
                              hipStream_t stream) {
    (void)in_sizes; (void)n_in; (void)out_size;
    const float* x     = (const float*)d_in[0];
    const float* query = (const float*)d_in[1];
    const float* wqk   = (const float*)d_in[2];
    const float* wv    = (const float*)d_in[3];
    const float* wproj = (const float*)d_in[4];
    const float* bproj = (const float*)d_in[5];
    const float* wpre  = (const float*)d_in[6];
    const float* wpost = (const float*)d_in[7];
    float* outp = (float*)d_out;

    if (ws_size >= (size_t)WS_ELEMS*2){
        u16* ws = (u16*)d_ws;
        convert_weights<<<256, 256, 0, stream>>>(wqk, wv, wproj, ws);
        hipFuncSetAttribute((const void*)gta_kernel<false>,
                            hipFuncAttributeMaxDynamicSharedMemorySize, LDS_BYTES);
        gta_kernel<false><<<2048, 512, LDS_BYTES, stream>>>(
            x, query, ws + WS_WQK, ws + WS_WV, ws + WS_WPJ,
            bproj, wpre, wpost, outp);
    } else {
        hipFuncSetAttribute((const void*)gta_kernel<true>,
                            hipFuncAttributeMaxDynamicSharedMemorySize, LDS_BYTES);
        gta_kernel<true><<<2048, 512, LDS_BYTES, stream>>>(
            x, query, wqk, wv, wproj, bproj, wpre, wpost, outp);
    }
}